// Round 1
// 85.983 us; speedup vs baseline: 1.0028x; 1.0028x over previous
//
#include <hip/hip_runtime.h>
#include <math.h>

#define NBINS 128
#define NFREQ 64
#define NH    4                  // harmonics kept (I5(1)=2.7e-4 dropped)
#define NSEG  (2*NH+1)           // 9 feature segments
#define KDIM  (NSEG*NFREQ)       // 576
#define KSTEPS (KDIM/32)         // 18
#define ROWF  (KDIM+8)           // 584 f16 row
#define ROWL  (NBINS+8)          // 136 f16 row
#define ROWP  68
#define MKEYS 32                 // keys per block (halves Cfrag L2 traffic vs 16)

typedef _Float16 f16x8 __attribute__((ext_vector_type(8)));
typedef _Float16 f16x2 __attribute__((ext_vector_type(2)));
typedef float    f32x4 __attribute__((ext_vector_type(4)));

#define MFMA16(A,B,C) __builtin_amdgcn_mfma_f32_16x16x32_f16((A),(B),(C),0,0,0)

// ---------------------------------------------------------------------------
// Prep: Fourier-fold von-Mises into GEMM coefficients.
// 128 blocks x 192 threads; thread = (m, group), group = (bin,f).
// Bessel series trimmed to 6 terms (kappa=1: term7 < 1e-9 rel, far below
// the fp16 Cfrag quantization).
// ---------------------------------------------------------------------------
__global__ __launch_bounds__(192) void prep_kernel(
    const float* __restrict__ mu, const float* __restrict__ kappa,
    const float* __restrict__ weight, const float* __restrict__ ref,
    const float* __restrict__ W1,
    _Float16* __restrict__ Cfrag, _Float16* __restrict__ W1h)
{
    __shared__ float red[3][64][10];

    const int t = threadIdx.x;           // 0..191
    const int m = t >> 6;                // 0..2
    const int g = t & 63;                // 0..63
    const int G = blockIdx.x * 64 + g;   // (bin,f) group, 0..8191
    const int f = G & 63;

    // W1 -> fp16 (8192 elems over 24576 threads)
    int wid = blockIdx.x * 192 + t;
    if (wid < NBINS * 64) W1h[wid] = (_Float16)W1[wid];

    const int idx = G * 3 + m;           // (bin*64+f)*3 + m  — coalesced-ish
    float kap = kappa[idx];
    float wgt = weight[idx];
    float mue = mu[idx] + ref[f];

    // I_0..I_4(kap) power series; all divisors are compile-time reciprocals.
    float I[NH + 1];
    {
        const float rfact[NH + 1] = {1.f, 1.f, 0.5f, 1.f / 6.f, 1.f / 24.f};
        float x2 = kap * 0.5f, x2sq = x2 * x2;
        float xk = 1.f;
        #pragma unroll
        for (int k = 0; k <= NH; ++k) {
            if (k > 0) xk *= x2;
            float term = xk * rfact[k];
            float s = term;
            #pragma unroll
            for (int j = 1; j <= 6; ++j) {
                term *= x2sq * (1.f / ((float)j * (float)(j + k)));
                s += term;
            }
            I[k] = s;
        }
    }
    float e = expf(-kap) * wgt;
    float c1, s1; sincosf(mue, &s1, &c1);
    float ck = 1.f, sk = 0.f;
    red[m][g][0] = e * I[0];
    #pragma unroll
    for (int k = 1; k <= NH; ++k) {
        float cn = ck * c1 - sk * s1;
        float sn = sk * c1 + ck * s1;
        ck = cn; sk = sn;                // cos(k*mue), sin(k*mue)
        red[m][g][2 * k - 1] = e * 2.f * I[k] * ck;
        red[m][g][2 * k]     = e * 2.f * I[k] * sk;
    }
    __syncthreads();

    if (t < 64) {
        int G2 = blockIdx.x * 64 + t;
        int bin = G2 >> 6, ff = G2 & 63, bt = bin >> 4;
        #pragma unroll
        for (int seg = 0; seg < NSEG; ++seg) {
            float v = red[0][t][seg] + red[1][t][seg] + red[2][t][seg];
            int q = seg * NFREQ + ff;
            int ks = q >> 5, kk = q & 31;
            int lane = (bin & 15) | (((kk >> 3) & 3) << 4);
            int elem = kk & 7;
            Cfrag[((size_t)(ks * 8 + bt) * 64 + lane) * 8 + elem] = (_Float16)v;
        }
    }
}

// ---------------------------------------------------------------------------
// Main: 256 blocks x 512 threads (8 waves), 32 keys/block -> 1 block/CU
// (same 8 waves/CU as before, but Cfrag is read once per 32 keys instead of
// once per 16 -> L2 traffic 74 MB -> 37 MB).
// Phase 1: Phi features in LDS (rotation recurrence, no trig).
// Phase 2: logits(32x128) = Phi(32x576) x C^T; wave w owns bin-tile bt=w
//          (16 bins) x 2 key-tiles.
// Phase 3: MLP via MFMA (wave -> (key-tile, 16 hidden)); reduce; sigmoid.
// ---------------------------------------------------------------------------
__global__ __launch_bounds__(512, 2) void main_kernel(
    const float* __restrict__ K, const int* __restrict__ kpos,
    const float* __restrict__ bias, const float* __restrict__ b1,
    const float* __restrict__ W2, const float* __restrict__ b2,
    const float* __restrict__ anchor_raw,
    const _Float16* __restrict__ Cfrag, const _Float16* __restrict__ W1h,
    float* __restrict__ out)
{
    __shared__ _Float16 PhiF[MKEYS * ROWF];   // 37376 B
    __shared__ _Float16 LgF[MKEYS * ROWL];    //  8704 B
    __shared__ float    Ps[MKEYS * ROWP];     //  8704 B
    __shared__ float    Pr[512];              //  2048 B   (~56.8 KB total)

    const int t  = threadIdx.x;
    const int n0 = blockIdx.x * MKEYS;

    // ---- Phase 1: features (32 keys x 32 float4-groups = 1024 items) ----
    #pragma unroll
    for (int it = 0; it < 2; ++it) {
        int p = it * 512 + t;
        int key = p >> 5, f2 = p & 31;
        float4 xy = *(const float4*)(K + (size_t)(n0 + key) * 128 + f2 * 4);
        float vs[2][NSEG];
        #pragma unroll
        for (int e = 0; e < 2; ++e) {
            float x = e ? xy.z : xy.x;
            float y = e ? xy.w : xy.y;
            float r2 = x * x + y * y;
            float inv = r2 > 0.f ? rsqrtf(r2) : 0.f;
            vs[e][0] = r2 * inv;          // mag
            float ca = x * inv, sa = y * inv;
            float mc = x, ms = y;         // mag*cos(kθ), mag*sin(kθ)
            vs[e][1] = mc; vs[e][2] = ms;
            #pragma unroll
            for (int h = 2; h <= NH; ++h) {
                float mc2 = mc * ca - ms * sa;
                float ms2 = ms * ca + mc * sa;
                mc = mc2; ms = ms2;
                vs[e][2 * h - 1] = mc; vs[e][2 * h] = ms;
            }
        }
        _Float16* dst = PhiF + key * ROWF + 2 * f2;
        #pragma unroll
        for (int s = 0; s < NSEG; ++s) {
            f16x2 pk; pk.x = (_Float16)vs[0][s]; pk.y = (_Float16)vs[1][s];
            *(f16x2*)(dst + s * 64) = pk;
        }
    }
    __syncthreads();

    // ---- Phase 2: feature GEMM (wave w -> bins 16w..16w+15, 2 key-tiles) ----
    const int l = t & 63, w = t >> 6;
    f32x4 acc[2] = {};
    const _Float16* phA = PhiF + (l & 15) * ROWF + (l >> 4) * 8;
    const _Float16* cb  = Cfrag + ((size_t)w * 64 + l) * 8;
    #define LA(KS, MT) (*(const f16x8*)(phA + (MT) * 16 * ROWF + (KS) * 32))
    #define LB(KS)     (*(const f16x8*)(cb + (size_t)(KS) * 4096))

    f16x8 b0 = LB(0), b1f = LB(1);
    f16x8 a0 = LA(0, 0), a1 = LA(0, 1);
    #pragma unroll
    for (int ks = 0; ks < KSTEPS; ++ks) {
        int kb = ks + 2 < KSTEPS ? ks + 2 : KSTEPS - 1;   // B prefetch depth 2
        f16x8 nb = LB(kb);
        int ka = ks + 1 < KSTEPS ? ks + 1 : KSTEPS - 1;   // A prefetch depth 1
        f16x8 na0 = LA(ka, 0), na1 = LA(ka, 1);
        acc[0] = MFMA16(a0, b0, acc[0]);
        acc[1] = MFMA16(a1, b0, acc[1]);
        a0 = na0; a1 = na1;
        b0 = b1f; b1f = nb;
    }
    #undef LA
    #undef LB

    // logits (+bias) -> LDS fp16, [key][bin] (A-fragment-readable)
    {
        int bin = 16 * w + (l & 15);
        float bbv = bias[bin];
        #pragma unroll
        for (int mt = 0; mt < 2; ++mt) {
            #pragma unroll
            for (int r = 0; r < 4; ++r) {
                int key = mt * 16 + (l >> 4) * 4 + r;  // D: col=lane&15, row=(lane>>4)*4+r
                LgF[key * ROWL + bin] = (_Float16)(acc[mt][r] + bbv);
            }
        }
    }
    __syncthreads();

    // ---- Phase 3: MLP layer 1 (M=32 keys, N=64 j, K=128 bins) ----
    // wave w -> key-tile mt=w>>2, hidden-tile jq=w&3 (16 j's)
    f32x4 hacc = {};
    {
        const int mt = w >> 2, jq = w & 3;
        const int j  = jq * 16 + (l & 15);
        const _Float16* lgA = LgF + (mt * 16 + (l & 15)) * ROWL + (l >> 4) * 8;
        const _Float16* wb  = W1h + (size_t)j * 128 + (l >> 4) * 8;
        #pragma unroll
        for (int ks = 0; ks < 4; ++ks) {
            f16x8 bfr = *(const f16x8*)(wb + ks * 32);
            f16x8 am  = *(const f16x8*)(lgA + ks * 32);
            hacc = MFMA16(am, bfr, hacc);
        }
        float b1j = b1[j], w2j = W2[j];
        #pragma unroll
        for (int r = 0; r < 4; ++r) {
            int key = mt * 16 + (l >> 4) * 4 + r;
            float h = hacc[r] + b1j;
            Ps[key * ROWP + j] = fmaxf(h, 0.f) * w2j;
        }
    }
    __syncthreads();

    // reduce 64 j per key: stage 1 (16 threads/key x 4 elems), stage 2 (32 keys)
    {
        int key = t >> 4, gg = t & 15;
        const float* p = Ps + key * ROWP + gg * 4;
        Pr[t] = (p[0] + p[1]) + (p[2] + p[3]);
    }
    __syncthreads();
    if (t < MKEYS) {
        const float* p = Pr + t * 16;
        float s = (((p[0] + p[1]) + (p[2] + p[3])) + ((p[4] + p[5]) + (p[6] + p[7])))
                + (((p[8] + p[9]) + (p[10] + p[11])) + ((p[12] + p[13]) + (p[14] + p[15])));
        float mlp = s + b2[0];
        float aw0 = log1pf(expf(anchor_raw[0]));
        float aw1 = log1pf(expf(anchor_raw[1]));
        float aw2 = log1pf(expf(anchor_raw[2]));
        int n = n0 + t;
        float pf = (float)kpos[n];
        float lp = log10f(fmaxf(pf, 1.f));
        float wgt;
        if      (lp < 3.f) wgt = aw0;
        else if (lp < 4.f) wgt = fmaf(aw1 - aw0, lp - 3.f, aw0);
        else if (lp < 5.f) wgt = fmaf(aw2 - aw1, lp - 4.f, aw1);
        else               wgt = aw2;
        float z = mlp * wgt;
        out[n] = 1.f / (1.f + expf(-z));
    }
}

extern "C" void kernel_launch(void* const* d_in, const int* in_sizes, int n_in,
                              void* d_out, int out_size, void* d_ws, size_t ws_size,
                              hipStream_t stream)
{
    const float* K    = (const float*)d_in[0];
    const int*   kpos = (const int*)d_in[1];
    const float* ref  = (const float*)d_in[2];
    const float* mu   = (const float*)d_in[3];
    const float* kap  = (const float*)d_in[4];
    const float* wgt  = (const float*)d_in[5];
    const float* bias = (const float*)d_in[6];
    const float* W1   = (const float*)d_in[7];
    const float* b1   = (const float*)d_in[8];
    const float* W2   = (const float*)d_in[9];
    const float* b2   = (const float*)d_in[10];
    const float* anc  = (const float*)d_in[11];
    float* out = (float*)d_out;

    int N = in_sizes[0] / (2 * NFREQ);   // 8192

    // Workspace: Cfrag 18*8*512 f16 = 147456 B; W1h 8192 f16 = 16384 B
    char* ws = (char*)d_ws;
    _Float16* Cfrag = (_Float16*)ws;
    _Float16* W1h   = (_Float16*)(ws + 147456);

    prep_kernel<<<128, 192, 0, stream>>>(mu, kap, wgt, ref, W1, Cfrag, W1h);
    main_kernel<<<N / MKEYS, 512, 0, stream>>>(K, kpos, bias, b1, W2, b2, anc,
                                               Cfrag, W1h, out);
}